// Round 3
// baseline (1507.119 us; speedup 1.0000x reference)
//
#include <hip/hip_runtime.h>
#include <stdint.h>

#define B_  128
#define G_  360
#define GI_ 174
#define EF_ 512
#define U_  512
#define AU_ 32
#define VOC_ 5000
#define T_  20

typedef short short8 __attribute__((ext_vector_type(8)));
typedef float floatx4 __attribute__((ext_vector_type(4)));

#define GLD16(gp, lp) __builtin_amdgcn_global_load_lds( \
    (const __attribute__((address_space(1))) void*)(gp), \
    (__attribute__((address_space(3))) void*)(lp), 16, 0, 0)

__device__ __forceinline__ unsigned short f2bf(float f){
  unsigned u = __float_as_uint(f);
  u += 0x7fffu + ((u>>16)&1u);
  return (unsigned short)(u>>16);
}
__device__ __forceinline__ float2 bfpair(unsigned u){
  float2 r; r.x = __uint_as_float(u<<16); r.y = __uint_as_float(u & 0xffff0000u); return r;
}
__device__ __forceinline__ unsigned packbf(float a, float b){
  return ((unsigned)f2bf(b)<<16) | (unsigned)f2bf(a);
}
__device__ __forceinline__ float sigmf(float x){ return 1.0f/(1.0f + __expf(-x)); }
__device__ __forceinline__ float tanhf_(float x){ return 1.0f - 2.0f/(1.0f + __expf(2.0f*x)); }
__device__ __forceinline__ float leaky_(float x){ return x >= 0.f ? x : 0.2f*x; }

// ---- device-scope grid barrier (all blocks co-resident: grid=128 on 256 CUs)
__device__ __forceinline__ void gbar(unsigned* cnt, unsigned target){
  __syncthreads();
  if (threadIdx.x == 0){
    __hip_atomic_fetch_add(cnt, 1u, __ATOMIC_RELEASE, __HIP_MEMORY_SCOPE_AGENT);
    while (__hip_atomic_load(cnt, __ATOMIC_ACQUIRE, __HIP_MEMORY_SCOPE_AGENT) < target)
      __builtin_amdgcn_s_sleep(2);
  }
  __syncthreads();
}

// ====================== k_cvt: conversions / gathers / transposes ==========
// [0,90) zero stats (+blk0 zeros barrier cnt) | [90,2138) Wstep | [2138,2146) bias_sum
// [2146,4706) emb gather | 4706 W1g/f1c | [4707,4739) dW1t | [4739,5059) dW2t
// big-path only: [5059,5419) featT | [5419,8299) encWt
__global__ __launch_bounds__(256) void k_cvt(
    const int* __restrict__ text, const float* __restrict__ emb,
    const float* __restrict__ Wih, const float* __restrict__ Whh,
    const float* __restrict__ bih, const float* __restrict__ bhh,
    const float* __restrict__ W1, const float* __restrict__ b1,
    const float* __restrict__ encg, const float* __restrict__ encb,
    const float* __restrict__ dW1, const float* __restrict__ dW2,
    const float* __restrict__ features, const float* __restrict__ encW,
    float* __restrict__ stats, unsigned short* __restrict__ Wstep,
    float* __restrict__ bias_sum, unsigned short* __restrict__ ASbuf,
    unsigned short* __restrict__ W1g, float* __restrict__ f1c,
    unsigned short* __restrict__ dW1t, unsigned short* __restrict__ dW2t,
    unsigned short* __restrict__ featT, unsigned short* __restrict__ encWt,
    unsigned* __restrict__ cnt)
{
  __shared__ float tile[64][65];
  const int blk = blockIdx.x, tid = threadIdx.x;
  if (blk < 90){
    if (blk == 0 && tid == 0) *cnt = 0u;
    int i = blk*1024 + tid*4;
    *(float4*)&stats[i] = make_float4(0.f,0.f,0.f,0.f);
  } else if (blk < 2138){
    int j = blk - 90;
    #pragma unroll
    for (int q=0;q<6;++q){
      int c = q*256 + tid;
      float v;
      if (c < 512)       v = Wih[(size_t)j*1024 + 512 + c];
      else if (c < 1024) v = Wih[(size_t)j*1024 + (c - 512)];
      else               v = Whh[(size_t)j*512 + (c - 1024)];
      Wstep[(size_t)j*1536 + c] = f2bf(v);
    }
  } else if (blk < 2146){
    int i = (blk-2138)*256 + tid;
    bias_sum[i] = bih[i] + bhh[i];
  } else if (blk < 4706){
    int r = blk - 2146; int t = r >> 7, b = r & 127;
    int idx = text[b*T_ + t];
    float2 v = *(const float2*)&emb[(size_t)idx*512 + 2*tid];
    ((unsigned*)ASbuf)[(((size_t)r*1536)>>1) + tid] = packbf(v.x, v.y);
  } else if (blk == 4706){
    if (tid < 32){
      float gw = 0.f, bw = 0.f;
      for (int k=0;k<512;++k){
        float wv = W1[(size_t)k*32 + tid];
        float gk = encg[k], bk = encb[k];
        W1g[(size_t)tid*512 + k] = f2bf(gk*wv);
        gw += gk*wv; bw += bk*wv;
      }
      f1c[tid] = gw; f1c[32+tid] = bw + b1[tid];
    }
  } else if (blk < 4739){
    int q = blk - 4707; int kt = q >> 2, nt = q & 3;
    int k0 = kt*64, n0 = nt*64;
    #pragma unroll
    for (int it=0; it<16; ++it){
      int idx = it*256 + tid; int kk = idx>>6, nn = idx&63;
      tile[kk][nn] = dW1[(size_t)(k0+kk)*256 + n0+nn];
    }
    __syncthreads();
    #pragma unroll
    for (int it=0; it<16; ++it){
      int idx = it*256 + tid; int nn = idx>>6, kk = idx&63;
      dW1t[(size_t)(n0+nn)*512 + k0+kk] = f2bf(tile[kk][nn]);
    }
  } else if (blk < 5059){
    int q = blk - 4739; int kt = q/80, nt = q - kt*80;
    int k0 = kt*64, n0 = nt*64;
    #pragma unroll
    for (int it=0; it<16; ++it){
      int idx = it*256 + tid; int kk = idx>>6, nn = idx&63;
      tile[kk][nn] = (n0+nn < VOC_) ? dW2[(size_t)(k0+kk)*VOC_ + n0+nn] : 0.f;
    }
    __syncthreads();
    #pragma unroll
    for (int it=0; it<16; ++it){
      int idx = it*256 + tid; int nn = idx>>6, kk = idx&63;
      dW2t[(size_t)(n0+nn)*256 + k0+kk] = f2bf(tile[kk][nn]);
    }
  } else if (blk < 5419){
    // featT[g][b][192] bf16 from features[b][g*174+k]
    int g = blk - 5059;
    #pragma unroll 4
    for (int it=0; it<48; ++it){
      int idx = it*256 + tid; int r = idx/96, q = idx - (idx/96)*96; int k = 2*q;
      float2 v = (k < GI_) ? *(const float2*)&features[(size_t)r*(G_*GI_) + (size_t)g*GI_ + k]
                           : make_float2(0.f,0.f);
      ((unsigned*)featT)[((size_t)(g*128 + r)*192 + k)>>1] = packbf(v.x, v.y);
    }
  } else {
    // encWt[g][n][192] bf16 from encW[g][k][n]
    int q = blk - 5419; int g = q >> 3; int n0 = (q & 7)*64;
    for (int c=0;c<3;++c){
      int k0 = c*64;
      #pragma unroll
      for (int it=0; it<16; ++it){
        int idx = it*256 + tid; int kk = idx>>6, nn = idx&63;
        tile[kk][nn] = (k0+kk < GI_) ? encW[((size_t)g*GI_ + k0+kk)*512 + n0+nn] : 0.f;
      }
      __syncthreads();
      #pragma unroll
      for (int it=0; it<8; ++it){
        int idx = it*256 + tid; int nn = idx>>5, kq = idx&31;
        ((unsigned*)encWt)[(((size_t)(g*512 + n0+nn)*192 + k0)>>1) + kq] =
            packbf(tile[2*kq][nn], tile[2*kq+1][nn]);
      }
      __syncthreads();
    }
  }
}

// ====================== k_enc2: MFMA GEMM from pre-converted bf16 ==========
__global__ __launch_bounds__(256) void k_enc2(
    const unsigned short* __restrict__ featT, const unsigned short* __restrict__ encWt,
    const float* __restrict__ encB,
    unsigned short* __restrict__ ybuf, float* __restrict__ stats)
{
  __shared__ __align__(16) unsigned short As[128*64];
  __shared__ __align__(16) unsigned short Bs[128*64];
  const int g = blockIdx.y, n0 = blockIdx.x*128;
  const int tid = threadIdx.x, w = tid>>6, l = tid&63;
  const int quad = l>>4, col16 = l&15;
  const int m0w = (w>>1)*64, n0w = (w&1)*64;
  const int arow = w*32, brow = w*32;

  const unsigned short* Ag = featT + (size_t)g*128*192 + (size_t)(arow + (l>>3))*192 + (l&7)*8;
  const unsigned short* Bg = encWt + ((size_t)g*512 + n0 + brow + (l>>3))*192 + (l&7)*8;

  floatx4 acc[4][4];
  #pragma unroll
  for (int mi=0;mi<4;++mi)
    #pragma unroll
    for (int ni=0;ni<4;++ni)
      acc[mi][ni] = (floatx4){0.f,0.f,0.f,0.f};

  for (int cc=0; cc<3; ++cc){
    int kc64 = cc*64;
    #pragma unroll
    for (int q=0;q<4;++q)
      GLD16(Ag + (size_t)q*8*192 + kc64, As + (arow + q*8)*64);
    #pragma unroll
    for (int q=0;q<4;++q)
      GLD16(Bg + (size_t)q*8*192 + kc64, Bs + (brow + q*8)*64);
    __syncthreads();
    #pragma unroll
    for (int kc=0;kc<2;++kc){
      int koff = kc*32 + quad*8;
      short8 af[4], bfr[4];
      #pragma unroll
      for (int mi=0;mi<4;++mi)
        af[mi] = *(const short8*)&As[(m0w + mi*16 + col16)*64 + koff];
      #pragma unroll
      for (int ni=0;ni<4;++ni)
        bfr[ni] = *(const short8*)&Bs[(n0w + ni*16 + col16)*64 + koff];
      #pragma unroll
      for (int mi=0;mi<4;++mi)
        #pragma unroll
        for (int ni=0;ni<4;++ni)
          acc[mi][ni] = __builtin_amdgcn_mfma_f32_16x16x32_bf16(af[mi], bfr[ni], acc[mi][ni], 0,0,0);
    }
    __syncthreads();
  }

  #pragma unroll
  for (int mi=0;mi<4;++mi){
    float sy[4] = {0.f,0.f,0.f,0.f};
    float sq[4] = {0.f,0.f,0.f,0.f};
    #pragma unroll
    for (int ni=0;ni<4;++ni){
      int nG = n0 + n0w + ni*16 + col16;
      float bv = encB[(size_t)g*512 + nG];
      #pragma unroll
      for (int reg=0;reg<4;++reg){
        int row = m0w + mi*16 + quad*4 + reg;
        float y = leaky_(acc[mi][ni][reg] + bv);
        unsigned short yh = f2bf(y);
        ybuf[((size_t)row*G_ + g)*512 + nG] = yh;
        float yr = __uint_as_float(((unsigned)yh)<<16);
        sy[reg] += yr; sq[reg] += yr*yr;
      }
    }
    #pragma unroll
    for (int reg=0; reg<4; ++reg){
      float a = sy[reg], bq = sq[reg];
      #pragma unroll
      for (int mk=1; mk<16; mk<<=1){ a += __shfl_xor(a, mk, 64); bq += __shfl_xor(bq, mk, 64); }
      if (col16 == 0){
        int row = m0w + mi*16 + quad*4 + reg;
        atomicAdd(&stats[((size_t)row*G_ + g)*2],     a);
        atomicAdd(&stats[((size_t)row*G_ + g)*2 + 1], bq);
      }
    }
  }
}

// ====================== legacy k_enc (fallback when ws is small) ==========
__device__ __forceinline__ int swzA(int row, int k){
  return row*192 + ((((k>>3) ^ (row&7)))<<3) + (k&7);
}
__device__ __forceinline__ int swzB(int row, int k){
  return row*64 + ((((k>>3) ^ (row&7)))<<3) + (k&7);
}
__global__ __launch_bounds__(256) void k_enc(
    const float* __restrict__ features, const float* __restrict__ encW,
    const float* __restrict__ encB,
    unsigned short* __restrict__ ybuf, float* __restrict__ stats)
{
  __shared__ __align__(16) unsigned short As[128*192];
  __shared__ __align__(16) unsigned short Bs[128*64];
  const int g = blockIdx.y, n0 = blockIdx.x*128;
  const int tid = threadIdx.x, w = tid>>6, l = tid&63;
  const int quad = l>>4, col16 = l&15;
  const int m0w = (w>>1)*64, n0w = (w&1)*64;

  for (int rr=0; rr<32; ++rr){
    int row = w*32 + rr;
    const float* fp = features + (size_t)row*(G_*GI_) + (size_t)g*GI_;
    float v0 = fp[l];
    float v1 = fp[l+64];
    float v2 = (l < 46) ? fp[l+128] : 0.f;
    As[swzA(row, l)]      = f2bf(v0);
    As[swzA(row, l+64)]   = f2bf(v1);
    As[swzA(row, l+128)]  = f2bf(v2);
  }

  floatx4 acc[4][4];
  #pragma unroll
  for (int mi=0;mi<4;++mi)
    #pragma unroll
    for (int ni=0;ni<4;++ni)
      acc[mi][ni] = (floatx4){0.f,0.f,0.f,0.f};

  for (int c=0; c<3; ++c){
    if (c > 0) __syncthreads();
    int kc0 = c*64;
    #pragma unroll
    for (int z=0; z<16; ++z){
      int k = kc0 + w + 4*z;
      int kk = w + 4*z;
      if (k < GI_){
        const float* wp = encW + ((size_t)g*GI_ + k)*512 + n0;
        Bs[swzB(l,    kk)] = f2bf(wp[l]);
        Bs[swzB(l+64, kk)] = f2bf(wp[l+64]);
      } else {
        Bs[swzB(l,    kk)] = 0;
        Bs[swzB(l+64, kk)] = 0;
      }
    }
    __syncthreads();
    #pragma unroll
    for (int it=0; it<2; ++it){
      int kg = c*64 + it*32 + quad*8;
      int kk = it*32 + quad*8;
      short8 af[4], bfr[4];
      #pragma unroll
      for (int mi=0;mi<4;++mi){
        int row = m0w + mi*16 + col16;
        af[mi] = *(const short8*)&As[row*192 + (((kg>>3) ^ (row&7))<<3)];
      }
      #pragma unroll
      for (int ni=0;ni<4;++ni){
        int rowb = n0w + ni*16 + col16;
        bfr[ni] = *(const short8*)&Bs[rowb*64 + (((kk>>3) ^ (rowb&7))<<3)];
      }
      #pragma unroll
      for (int mi=0;mi<4;++mi)
        #pragma unroll
        for (int ni=0;ni<4;++ni)
          acc[mi][ni] = __builtin_amdgcn_mfma_f32_16x16x32_bf16(af[mi], bfr[ni], acc[mi][ni], 0,0,0);
    }
  }

  #pragma unroll
  for (int mi=0;mi<4;++mi){
    float sy[4] = {0.f,0.f,0.f,0.f};
    float sq[4] = {0.f,0.f,0.f,0.f};
    #pragma unroll
    for (int ni=0;ni<4;++ni){
      int nG = n0 + n0w + ni*16 + col16;
      float bv = encB[(size_t)g*512 + nG];
      #pragma unroll
      for (int reg=0;reg<4;++reg){
        int row = m0w + mi*16 + quad*4 + reg;
        float y = leaky_(acc[mi][ni][reg] + bv);
        unsigned short yh = f2bf(y);
        ybuf[((size_t)row*G_ + g)*512 + nG] = yh;
        float yr = __uint_as_float(((unsigned)yh)<<16);
        sy[reg] += yr; sq[reg] += yr*yr;
      }
    }
    #pragma unroll
    for (int reg=0; reg<4; ++reg){
      float a = sy[reg], bq = sq[reg];
      #pragma unroll
      for (int mk=1; mk<16; mk<<=1){ a += __shfl_xor(a, mk, 64); bq += __shfl_xor(bq, mk, 64); }
      if (col16 == 0){
        int row = m0w + mi*16 + quad*4 + reg;
        atomicAdd(&stats[((size_t)row*G_ + g)*2],     a);
        atomicAdd(&stats[((size_t)row*G_ + g)*2 + 1], bq);
      }
    }
  }
}

// ====================== generic bf16 MFMA GEMM (A[M][K], Bt[N][K]) ==========
// MODE 1: f1; MODE 2: dec1; MODE 3: dec2
template<int TN, int NBK, int MODE>
__global__ __launch_bounds__(256) void k_gemm(
    const unsigned short* __restrict__ A, int lda,
    const unsigned short* __restrict__ Bt, int ldb,
    const float* __restrict__ bias,
    float* __restrict__ outf, unsigned short* __restrict__ outh,
    const float* __restrict__ stats, float* __restrict__ stats2,
    const float* __restrict__ f1c)
{
  constexpr int NI = TN/32;
  __shared__ __align__(16) unsigned short As[128*64];
  __shared__ __align__(16) unsigned short Bs[TN*64];
  const int tid = threadIdx.x;
  const int w = tid >> 6, l = tid & 63;
  const int n0 = blockIdx.x * TN;
  const int r0 = blockIdx.y * 128;
  const int quad = l>>4, col16 = l&15;
  const int m0w = (w>>1)*64, n0w = (w&1)*(TN/2);
  const int arow = w*32, brow = w*(TN/4);

  const unsigned short* Ag = A + (size_t)(r0 + arow + (l>>3))*lda + (l&7)*8;
  const unsigned short* Bg = Bt + (size_t)(n0 + brow + (l>>3))*ldb + (l&7)*8;

  floatx4 acc[4][NI];
  #pragma unroll
  for (int mi=0;mi<4;++mi)
    #pragma unroll
    for (int ni=0;ni<NI;++ni)
      acc[mi][ni] = (floatx4){0.f,0.f,0.f,0.f};

  for (int it=0; it<NBK; ++it){
    int k0 = it*64;
    #pragma unroll
    for (int q=0;q<4;++q)
      GLD16(Ag + (size_t)q*8*lda + k0, As + (arow + q*8)*64);
    #pragma unroll
    for (int q=0;q<TN/32;++q)
      GLD16(Bg + (size_t)q*8*ldb + k0, Bs + (brow + q*8)*64);
    __syncthreads();
    #pragma unroll
    for (int kc=0;kc<2;++kc){
      int koff = kc*32 + quad*8;
      short8 af[4], bfr[NI];
      #pragma unroll
      for (int mi=0;mi<4;++mi)
        af[mi] = *(const short8*)&As[(m0w + mi*16 + col16)*64 + koff];
      #pragma unroll
      for (int ni=0;ni<NI;++ni)
        bfr[ni] = *(const short8*)&Bs[(n0w + ni*16 + col16)*64 + koff];
      #pragma unroll
      for (int mi=0;mi<4;++mi)
        #pragma unroll
        for (int ni=0;ni<NI;++ni)
          acc[mi][ni] = __builtin_amdgcn_mfma_f32_16x16x32_bf16(af[mi], bfr[ni], acc[mi][ni], 0,0,0);
    }
    __syncthreads();
  }

  if constexpr (MODE == 1){
    int nG = n0w + col16;
    float gw = f1c[nG], bwv = f1c[32+nG];
    #pragma unroll
    for (int mi=0; mi<4; ++mi)
      #pragma unroll
      for (int reg=0; reg<4; ++reg){
        int r = r0 + m0w + mi*16 + quad*4 + reg;
        float2 st = *(const float2*)&stats[(size_t)r*2];
        float m = st.x * (1.f/512.f);
        float var = st.y * (1.f/512.f) - m*m;
        float rs = rsqrtf(var + 1e-5f);
        float v = rs*(acc[mi][0][reg] - m*gw) + bwv;
        v = v > 0.f ? v : 0.f;
        outf[(size_t)r*32 + nG] = v;
        if (((w&1)==0) && col16==0){
          stats2[(size_t)r*2] = m; stats2[(size_t)r*2+1] = rs;
        }
      }
  } else if constexpr (MODE == 2){
    #pragma unroll
    for (int ni=0; ni<NI; ++ni){
      int nG = n0 + n0w + ni*16 + col16;
      float bv = bias[nG];
      #pragma unroll
      for (int mi=0; mi<4; ++mi)
        #pragma unroll
        for (int reg=0; reg<4; ++reg){
          int r = r0 + m0w + mi*16 + quad*4 + reg;
          outh[(size_t)r*256 + nG] = f2bf(leaky_(acc[mi][ni][reg] + bv));
        }
    }
  } else {
    #pragma unroll
    for (int ni=0; ni<NI; ++ni){
      int nG = n0 + n0w + ni*16 + col16;
      if (nG < VOC_){
        float bv = bias[nG];
        #pragma unroll
        for (int mi=0; mi<4; ++mi)
          #pragma unroll
          for (int reg=0; reg<4; ++reg){
            int r = r0 + m0w + mi*16 + quad*4 + reg;
            int bb = r & 127, tt = r >> 7;
            outf[((size_t)bb*T_ + tt)*VOC_ + nG] = acc[mi][ni][reg] + bv;
          }
      }
    }
  }
}

// ====================== attention for one batch row (inlined into k_loop) ==========
__device__ __forceinline__ void attn_block(
    int b, int tid,
    float* a_s, float* sc, float* hred, float* h2s, float* red, float* mrs,
    const float* __restrict__ W2, const float* __restrict__ b2,
    const float* __restrict__ Vv, const float* __restrict__ bV,
    const float* __restrict__ f1, const unsigned short* __restrict__ ybuf,
    const float* __restrict__ stats2,
    const float* __restrict__ encg, const float* __restrict__ encb,
    unsigned short* __restrict__ slot, float* __restrict__ att_row)
{
  const int wv = tid >> 6, ln = tid & 63;
  // h2 = relu(a @ W2 + b2)
  {
    int u = tid & 31, ch = tid >> 5;
    float p = 0.f;
    const float* w2p = W2 + (size_t)ch*64*32 + u;
    const float* ap = a_s + ch*64;
    #pragma unroll 8
    for (int e=0;e<64;++e) p += ap[e]*w2p[(size_t)e*32];
    hred[ch*32+u] = p;
  }
  __syncthreads();
  if (tid < 32){
    float p = hred[tid];
    #pragma unroll
    for (int ch=1; ch<8; ++ch) p += hred[ch*32+tid];
    p += b2[tid];
    h2s[tid] = p>0.f? p:0.f;
  }
  __syncthreads();
  float bVv = bV[0];
  for (int gg = tid; gg < G_; gg += 256){
    const float* fp = f1 + ((size_t)b*G_ + gg)*32;
    float s = bVv;
    #pragma unroll
    for (int u=0;u<32;++u) s += tanhf_(fp[u] + h2s[u]) * Vv[u];
    sc[gg] = s;
  }
  __syncthreads();
  float mx = -1e30f;
  for (int gg=tid; gg<G_; gg+=256) mx = fmaxf(mx, sc[gg]);
  #pragma unroll
  for (int mk=1;mk<64;mk<<=1) mx = fmaxf(mx, __shfl_xor(mx,mk,64));
  if (ln==0) red[wv]=mx;
  __syncthreads();
  if (tid==0) red[0] = fmaxf(fmaxf(red[0],red[1]),fmaxf(red[2],red[3]));
  __syncthreads();
  mx = red[0];
  float psum = 0.f;
  for (int gg=tid; gg<G_; gg+=256){
    float e = __expf(sc[gg]-mx);
    sc[gg] = e; psum += e;
  }
  #pragma unroll
  for (int mk=1;mk<64;mk<<=1) psum += __shfl_xor(psum,mk,64);
  if (ln==0) red[8+wv]=psum;
  __syncthreads();
  if (tid==0) red[8] = red[8]+red[9]+red[10]+red[11];
  __syncthreads();
  float inv = 1.f/red[8];
  float Mop = 0.f;
  for (int gg=tid; gg<G_; gg+=256){
    float wg = sc[gg]*inv;
    att_row[gg] = wg;
    float2 st = *(const float2*)&stats2[((size_t)b*G_+gg)*2];
    sc[gg] = wg*st.y;
    Mop += wg*st.x*st.y;
  }
  #pragma unroll
  for (int mk=1;mk<64;mk<<=1) Mop += __shfl_xor(Mop,mk,64);
  if (ln==0) red[4+wv] = Mop;
  __syncthreads();
  if (tid==0) mrs[0] = red[4]+red[5]+red[6]+red[7];
  __syncthreads();
  float Mo = mrs[0];
  // ctx = encg*(sum_g w' y) - encg*Mo + encb, bf16 into slot[.,512:1024)
  {
    const unsigned* fp = (const unsigned*)ybuf + ((size_t)b*G_)*256 + tid;
    float c0a=0.f, c1a=0.f, c0b=0.f, c1b=0.f;
    for (int gg=0; gg<G_; gg+=8){
      unsigned u0 = fp[(size_t)(gg+0)*256];
      unsigned u1 = fp[(size_t)(gg+1)*256];
      unsigned u2 = fp[(size_t)(gg+2)*256];
      unsigned u3 = fp[(size_t)(gg+3)*256];
      unsigned u4 = fp[(size_t)(gg+4)*256];
      unsigned u5 = fp[(size_t)(gg+5)*256];
      unsigned u6 = fp[(size_t)(gg+6)*256];
      unsigned u7 = fp[(size_t)(gg+7)*256];
      float2 p0=bfpair(u0),p1=bfpair(u1),p2=bfpair(u2),p3=bfpair(u3);
      float2 p4=bfpair(u4),p5=bfpair(u5),p6=bfpair(u6),p7=bfpair(u7);
      float w0=sc[gg+0],w1=sc[gg+1],w2=sc[gg+2],w3=sc[gg+3];
      float w4=sc[gg+4],w5=sc[gg+5],w6=sc[gg+6],w7=sc[gg+7];
      c0a += w0*p0.x + w2*p2.x + w4*p4.x + w6*p6.x;
      c1a += w0*p0.y + w2*p2.y + w4*p4.y + w6*p6.y;
      c0b += w1*p1.x + w3*p3.x + w5*p5.x + w7*p7.x;
      c1b += w1*p1.y + w3*p3.y + w5*p5.y + w7*p7.y;
    }
    float c0v = c0a + c0b, c1v = c1a + c1b;
    int e0 = 2*tid;
    float ctx0 = encg[e0]  *(c0v - Mo) + encb[e0];
    float ctx1 = encg[e0+1]*(c1v - Mo) + encb[e0+1];
    ((unsigned*)slot)[(((size_t)b*1536 + 512)>>1) + tid] = packbf(ctx0, ctx1);
  }
}

// ====================== persistent recurrence kernel ==========
// 128 blocks. Per step: phase A = gates GEMM (32 n-tiles x 4 K-splits),
// grid barrier, phase B = cell+LN+attention (block b = batch row b).
__global__ __launch_bounds__(256) void k_loop(
    const unsigned short* __restrict__ Wstep, const float* __restrict__ bias_sum,
    const float* __restrict__ c0, const float* __restrict__ a0,
    const float* __restrict__ lng, const float* __restrict__ lnb,
    const float* __restrict__ W2, const float* __restrict__ b2,
    const float* __restrict__ Vv, const float* __restrict__ bV,
    const float* __restrict__ f1, const unsigned short* __restrict__ ybuf,
    const float* __restrict__ stats2,
    const float* __restrict__ encg, const float* __restrict__ encb,
    unsigned short* __restrict__ ASbuf, unsigned short* __restrict__ a_bf,
    float* __restrict__ gpart, float* __restrict__ att,
    unsigned* __restrict__ cnt)
{
  __shared__ __align__(16) unsigned short As[128*64];
  __shared__ __align__(16) unsigned short Bs[64*64];
  __shared__ float a_s[512];
  __shared__ float sc[G_];
  __shared__ float hred[256];
  __shared__ float h2s[32];
  __shared__ float red[16];
  __shared__ float mrs[2];
  const int b = blockIdx.x, tid = threadIdx.x;
  const int w = tid>>6, l = tid&63;
  const int wv = w, ln = l;
  const int quad = l>>4, col16 = l&15;

  float cprev0 = c0[(size_t)b*512 + tid];
  float cprev1 = c0[(size_t)b*512 + tid + 256];
  unsigned bt = 128;

  // ---- init: a = a0 -> slot0 a-part; attention(a0) -> att[:,0], slot0 ctx
  {
    float av0 = a0[(size_t)b*512 + tid];
    float av1 = a0[(size_t)b*512 + tid + 256];
    a_s[tid] = av0; a_s[tid+256] = av1;
    ASbuf[(size_t)b*1536 + 1024 + tid]       = f2bf(av0);
    ASbuf[(size_t)b*1536 + 1024 + tid + 256] = f2bf(av1);
  }
  __syncthreads();
  attn_block(b, tid, a_s, sc, hred, h2s, red, mrs,
             W2, b2, Vv, bV, f1, ybuf, stats2, encg, encb,
             ASbuf, att + ((size_t)b*T_ + 0)*G_);
  gbar(cnt, bt); bt += 128;

  const int nt = b & 31, ks = b >> 5;
  const int n0 = nt*64, k0 = ks*384;
  const int m0w = (w>>1)*64, n0wA = (w&1)*32;
  const int arow = w*32, brow = w*16;

  for (int t=0; t<T_; ++t){
    // ---------- phase A: partial gates GEMM ----------
    {
      const unsigned short* Ag = ASbuf + (size_t)t*196608
          + (size_t)(arow + (l>>3))*1536 + (k0 + (l&7)*8);
      const unsigned short* Bg = Wstep
          + (size_t)(n0 + brow + (l>>3))*1536 + (k0 + (l&7)*8);
      floatx4 acc[4][2];
      #pragma unroll
      for (int mi=0;mi<4;++mi){ acc[mi][0]=(floatx4){0,0,0,0}; acc[mi][1]=(floatx4){0,0,0,0}; }
      for (int cc=0; cc<6; ++cc){
        int kc64 = cc*64;
        #pragma unroll
        for (int q=0;q<4;++q)
          GLD16(Ag + (size_t)q*8*1536 + kc64, As + (arow + q*8)*64);
        #pragma unroll
        for (int q=0;q<2;++q)
          GLD16(Bg + (size_t)q*8*1536 + kc64, Bs + (brow + q*8)*64);
        __syncthreads();
        #pragma unroll
        for (int kc=0;kc<2;++kc){
          int koff = kc*32 + quad*8;
          short8 af[4], bfr[2];
          #pragma unroll
          for (int mi=0;mi<4;++mi)
            af[mi] = *(const short8*)&As[(m0w + mi*16 + col16)*64 + koff];
          #pragma unroll
          for (int ni=0;ni<2;++ni)
            bfr[ni] = *(const short8*)&Bs[(n0wA + ni*16 + col16)*64 + koff];
          #pragma unroll
          for (int mi=0;mi<4;++mi)
            #pragma unroll
            for (int ni=0;ni<2;++ni)
              acc[mi][ni] = __builtin_amdgcn_mfma_f32_16x16x32_bf16(af[mi], bfr[ni], acc[mi][ni], 0,0,0);
        }
        __syncthreads();
      }
      #pragma unroll
      for (int ni=0;ni<2;++ni){
        int nG = n0 + n0wA + ni*16 + col16;
        #pragma unroll
        for (int mi=0;mi<4;++mi)
          #pragma unroll
          for (int reg=0;reg<4;++reg){
            int r = m0w + mi*16 + quad*4 + reg;
            gpart[(size_t)ks*262144 + (size_t)r*2048 + nG] = acc[mi][ni][reg];
          }
      }
    }
    gbar(cnt, bt); bt += 128;

    // ---------- phase B: cell + LN + attention ----------
    {
      float ggv[2][4];
      #pragma unroll
      for (int q=0;q<2;++q){
        int u = tid + q*256;
        #pragma unroll
        for (int gate=0; gate<4; ++gate){
          float s = bias_sum[gate*512+u];
          #pragma unroll
          for (int kq=0; kq<4; ++kq)
            s += gpart[(size_t)kq*262144 + (size_t)b*2048 + gate*512 + u];
          ggv[q][gate] = s;
        }
      }
      float hl2[2];
      {
        float c = sigmf(ggv[0][1])*cprev0 + sigmf(ggv[0][0])*tanhf_(ggv[0][2]);
        cprev0 = c;
        hl2[0] = leaky_(sigmf(ggv[0][3])*tanhf_(c));
        c = sigmf(ggv[1][1])*cprev1 + sigmf(ggv[1][0])*tanhf_(ggv[1][2]);
        cprev1 = c;
        hl2[1] = leaky_(sigmf(ggv[1][3])*tanhf_(c));
      }
      float s = hl2[0]+hl2[1], ss = hl2[0]*hl2[0]+hl2[1]*hl2[1];
      #pragma unroll
      for (int mk=1;mk<64;mk<<=1){ s += __shfl_xor(s,mk,64); ss += __shfl_xor(ss,mk,64); }
      if (ln==0){ red[wv]=s; red[8+wv]=ss; }
      __syncthreads();
      if (tid==0){
        float S  = red[0]+red[1]+red[2]+red[3];
        float SS = red[8]+red[9]+red[10]+red[11];
        float mean = S*(1.f/512.f);
        float var  = SS*(1.f/512.f) - mean*mean;
        mrs[0]=mean; mrs[1]=rsqrtf(var+1e-5f);
      }
      __syncthreads();
      float mean = mrs[0], rstd = mrs[1];
      unsigned short* slot = ASbuf + (size_t)(t+1)*196608;
      #pragma unroll
      for (int q=0;q<2;++q){
        int u = tid + q*256;
        float av = (hl2[q]-mean)*rstd*lng[u] + lnb[u];
        a_s[u] = av;
        unsigned short ah = f2bf(av);
        a_bf[((size_t)t*128 + b)*512 + u] = ah;
        if (t < T_-1) slot[(size_t)b*1536 + 1024 + u] = ah;
      }
      __syncthreads();
      if (t < T_-1){
        attn_block(b, tid, a_s, sc, hred, h2s, red, mrs,
                   W2, b2, Vv, bV, f1, ybuf, stats2, encg, encb,
                   slot, att + ((size_t)b*T_ + t+1)*G_);
      }
    }
    gbar(cnt, bt); bt += 128;
  }
}

// ====================== in-place row softmax over VOC ==========
__global__ __launch_bounds__(256) void k_softmax(float* __restrict__ outp)
{
  __shared__ float red[8];
  const size_t row = (size_t)blockIdx.x * VOC_;
  const int tid = threadIdx.x;
  const int wv = tid >> 6, ln = tid & 63;
  float v[20];
  float mx = -1e30f;
  #pragma unroll
  for (int k=0;k<20;++k){
    int idx = tid + k*256;
    v[k] = (idx < VOC_) ? outp[row+idx] : -1e30f;
    mx = fmaxf(mx, v[k]);
  }
  #pragma unroll
  for (int mk=1;mk<64;mk<<=1) mx = fmaxf(mx,__shfl_xor(mx,mk,64));
  if (ln==0) red[wv] = mx;
  __syncthreads();
  if (tid==0) red[0]=fmaxf(fmaxf(red[0],red[1]),fmaxf(red[2],red[3]));
  __syncthreads();
  mx = red[0];
  float s=0.f;
  #pragma unroll
  for (int k=0;k<20;++k){ v[k] = __expf(v[k]-mx); s += v[k]; }
  #pragma unroll
  for (int mk=1;mk<64;mk<<=1) s += __shfl_xor(s,mk,64);
  if (ln==0) red[4+wv]=s;
  __syncthreads();
  if (tid==0) red[4]=red[4]+red[5]+red[6]+red[7];
  __syncthreads();
  float inv = 1.f/red[4];
  #pragma unroll
  for (int k=0;k<20;++k){
    int idx = tid + k*256;
    if (idx < VOC_) outp[row+idx] = v[k]*inv;
  }
}

extern "C" void kernel_launch(void* const* d_in, const int* in_sizes, int n_in,
                              void* d_out, int out_size, void* d_ws, size_t ws_size,
                              hipStream_t stream) {
  const float* features = (const float*)d_in[0];
  const int*   text     = (const int*)d_in[1];
  const float* a0    = (const float*)d_in[2];
  const float* c0    = (const float*)d_in[3];
  const float* encW  = (const float*)d_in[4];
  const float* encB  = (const float*)d_in[5];
  const float* encLNg= (const float*)d_in[6];
  const float* encLNb= (const float*)d_in[7];
  const float* attnW1= (const float*)d_in[8];
  const float* attnb1= (const float*)d_in[9];
  const float* attnW2= (const float*)d_in[10];
  const float* attnb2= (const float*)d_in[11];
  const float* attnV = (const float*)d_in[12];
  const float* attnbV= (const float*)d_in[13];
  const float* emb   = (const float*)d_in[14];
  const float* Wih   = (const float*)d_in[15];
  const float* Whh   = (const float*)d_in[16];
  const float* bih   = (const float*)d_in[17];
  const float* bhh   = (const float*)d_in[18];
  const float* lng   = (const float*)d_in[19];
  const float* lnb   = (const float*)d_in[20];
  const float* dW1   = (const float*)d_in[21];
  const float* db1   = (const float*)d_in[22];
  const float* dW2   = (const float*)d_in[23];
  const float* db2   = (const float*)d_in[24];

  uint8_t* w8 = (uint8_t*)d_ws;
  unsigned short* ybuf   = (unsigned short*)(w8);              // 47,185,920
  float*          stats  = (float*)(w8 + 47185920);            //    368,640
  float*          stats2 = (float*)(w8 + 47554560);            //    368,640
  float*          f1b    = (float*)(w8 + 47923200);            //  5,898,240
  unsigned short* ASbuf  = (unsigned short*)(w8 + 53821440);   //  7,864,320
  unsigned short* Wstep  = (unsigned short*)(w8 + 61685760);   //  6,291,456
  float*          bias_sum=(float*)(w8 + 67977216);            //      8,192
  unsigned short* W1g    = (unsigned short*)(w8 + 67985408);   //     32,768
  float*          f1c    = (float*)(w8 + 68018176);            //        256
  unsigned short* dW1t   = (unsigned short*)(w8 + 68018432);   //    262,144
  unsigned short* dW2t   = (unsigned short*)(w8 + 68280576);   //  2,621,440
  float*          gpart  = (float*)(w8 + 70902016);            //  4,194,304
  unsigned short* a_bf   = (unsigned short*)(w8 + 75096320);   //  2,621,440
  unsigned short* d1bf   = (unsigned short*)(w8 + 77717760);   //  1,310,720
  unsigned*       cnt    = (unsigned*)(w8 + 79028480);         //        256
  unsigned short* featT  = (unsigned short*)(w8 + 79028736);   // 17,694,720
  unsigned short* encWt  = (unsigned short*)(w8 + 96723456);   // 70,778,880
  const size_t NEEDED_BIG = 167502336;
  const bool big = (ws_size >= NEEDED_BIG);

  float* outp = (float*)d_out;
  float* att  = outp + 12800000;   // [B][T][G]

  hipLaunchKernelGGL(k_cvt, dim3(big ? 8299 : 5059), dim3(256), 0, stream,
                     text, emb, Wih, Whh, bih, bhh, attnW1, attnb1,
                     encLNg, encLNb, dW1, dW2, features, encW,
                     stats, Wstep, bias_sum, ASbuf, W1g, f1c, dW1t, dW2t,
                     featT, encWt, cnt);
  if (big){
    hipLaunchKernelGGL(k_enc2, dim3(4,360), dim3(256), 0, stream,
                       featT, encWt, encB, ybuf, stats);
  } else {
    hipLaunchKernelGGL(k_enc, dim3(4,360), dim3(256), 0, stream,
                       features, encW, encB, ybuf, stats);
  }
  hipLaunchKernelGGL((k_gemm<32,8,1>), dim3(1,360), dim3(256), 0, stream,
                     ybuf, 512, W1g, 512, (const float*)nullptr,
                     f1b, (unsigned short*)nullptr, stats, stats2, f1c);
  hipLaunchKernelGGL(k_loop, dim3(128), dim3(256), 0, stream,
                     Wstep, bias_sum, c0, a0, lng, lnb,
                     attnW2, attnb2, attnV, attnbV,
                     f1b, ybuf, stats2, encLNg, encLNb,
                     ASbuf, a_bf, gpart, att, cnt);
  hipLaunchKernelGGL((k_gemm<128,8,2>), dim3(2,20), dim3(256), 0, stream,
                     a_bf, 512, dW1t, 512, db1,
                     (float*)nullptr, d1bf, (const float*)nullptr, (float*)nullptr,
                     (const float*)nullptr);
  hipLaunchKernelGGL((k_gemm<128,4,3>), dim3(40,20), dim3(256), 0, stream,
                     d1bf, 256, dW2t, 256, db2,
                     outp, (unsigned short*)nullptr, (const float*)nullptr,
                     (float*)nullptr, (const float*)nullptr);
  hipLaunchKernelGGL(k_softmax, dim3(2560), dim3(256), 0, stream, outp);
}